// Round 2
// baseline (2100.377 us; speedup 1.0000x reference)
//
#include <hip/hip_runtime.h>
#include <math.h>

// ---------------------------------------------------------------------------
// SNN forward:  conv1+pool (parallel, chunked over T) ->
//               [lif0 -> conv2+pool -> lif2] (seq t, chunked, state in ws) ->
//               -> lif_rec(l1)+LI readout, lif_rec(cl)+LI readout (seq t)
// Round-2 fix: workspace footprint is now ws_size-aware (chunked T pipeline,
// parity-double-buffered chunk state). Round-1 used 35.3 MB unconditionally;
// OOB ws writes corrupted neighbor buffers -> replays diverged.
// ---------------------------------------------------------------------------

#define BATCH 32
#define TSTEPS 150
#define C1N 1470            // 30*7*7 (trimmed: pooled conv2 only needs 7x7)
#define ZSEQN 70
#define HID1 512
#define HID2 1024
#define K1CAT 582           // 70 + 512
#define K2CAT 1094          // 70 + 1024

#define N_Z    (BATCH*TSTEPS*ZSEQN)   // 336,000
#define N_W1T  (K1CAT*HID1)           // 297,984
#define N_W2T  (K2CAT*HID2)           // 1,120,256
#define N_ST0  (BATCH*2*C1N)          // 94,080  (v,i of lif0 per batch)
#define N_ST2  (BATCH*2*ZSEQN)        // 4,480   (v,i of lif2 per batch)

// -------------------------------------------------------------------- K0 ---
__global__ void prep_weights(const float* __restrict__ l1_in_w,
                             const float* __restrict__ l1_rec_w,
                             const float* __restrict__ cl_in_w,
                             const float* __restrict__ cl_rec_w,
                             float* __restrict__ w1t,
                             float* __restrict__ w2t) {
    int idx = blockIdx.x * blockDim.x + threadIdx.x;
    int stride = gridDim.x * blockDim.x;
    for (int e = idx; e < N_W1T; e += stride) {
        int j = e / HID1, o = e - j * HID1;
        w1t[e] = (j < 70) ? l1_in_w[o * 70 + j] : l1_rec_w[o * HID1 + (j - 70)];
    }
    for (int e = idx; e < N_W2T; e += stride) {
        int j = e / HID2, o = e - j * HID2;
        w2t[e] = (j < 70) ? cl_in_w[o * 70 + j] : cl_rec_w[o * HID2 + (j - 70)];
    }
}

// -------------------------------------------------------------------- K1 ---
// conv1 (2->30, 7x7, VALID) + maxpool3 for one (b,t) frame per WG.
// grid = BATCH*CH; block bt = b*CH + tc, absolute t = t0 + tc.
__global__ __launch_bounds__(640) void conv1_pool(const float* __restrict__ x,
                                                  const float* __restrict__ w1,
                                                  const float* __restrict__ b1,
                                                  float* __restrict__ c1buf,
                                                  int t0, int CH) {
    __shared__ float img[2 * 34 * 34];      // 9.25 KB
    __shared__ float w1s[30 * 2 * 49];      // 11.76 KB
    __shared__ float crow[630 * 21];        // 52.9 KB   [oc*21+cy][cx]
    int bid = blockIdx.x;
    int b = bid / CH, tc = bid - b * CH;
    int t = t0 + tc;
    int tid = threadIdx.x;
    const float* xin = x + (size_t)(b * TSTEPS + t) * 2312;
    for (int e = tid; e < 2312; e += 640) img[e] = xin[e];
    for (int e = tid; e < 2940; e += 640) w1s[e] = w1[e];
    __syncthreads();
    if (tid < 630) {
        int oc = tid / 21, cy = tid - oc * 21;   // conv row cy in [0,21)
        float acc[21];
        #pragma unroll
        for (int j = 0; j < 21; ++j) acc[j] = 0.f;
        #pragma unroll
        for (int ic = 0; ic < 2; ++ic) {
            const float* irow0 = &img[ic * 1156];
            const float* wrow = &w1s[(oc * 2 + ic) * 49];
            #pragma unroll
            for (int ky = 0; ky < 7; ++ky) {
                const float* ir = &irow0[(cy + ky) * 34];
                float r[27];
                #pragma unroll
                for (int j = 0; j < 27; ++j) r[j] = ir[j];
                #pragma unroll
                for (int kx = 0; kx < 7; ++kx) {
                    float w = wrow[ky * 7 + kx];
                    #pragma unroll
                    for (int cx = 0; cx < 21; ++cx)
                        acc[cx] = fmaf(r[cx + kx], w, acc[cx]);
                }
            }
        }
        #pragma unroll
        for (int cx = 0; cx < 21; ++cx) crow[tid * 21 + cx] = acc[cx];
    }
    __syncthreads();
    float* c1 = c1buf + (size_t)bid * C1N;
    for (int p = tid; p < C1N; p += 640) {
        int oc = p / 49; int r = p - oc * 49; int py = r / 7, px = r - py * 7;
        float m = -1e30f;
        #pragma unroll
        for (int dy = 0; dy < 3; ++dy) {
            int rowid = oc * 21 + 3 * py + dy;
            #pragma unroll
            for (int dx = 0; dx < 3; ++dx)
                m = fmaxf(m, crow[rowid * 21 + 3 * px + dx]);
        }
        c1[p] = m + b1[oc];
    }
}

// -------------------------------------------------------------------- K2 ---
// Sequential conv chain over one T-chunk. 8 WGs per batch; each WG keeps a
// private full lif0 state (identical across WGs -> deterministic) and owns
// ~9 conv2 output channels. Chunk state persisted via st*_in/st*_out
// (parity double-buffered on the host side: read [par], write [par^1]).
__global__ __launch_bounds__(320) void conv2_chain(const float* __restrict__ w2,
                                                   const float* __restrict__ b2,
                                                   const float* __restrict__ c1buf,
                                                   float* __restrict__ zbuf,
                                                   const float* __restrict__ st0_in,
                                                   float* __restrict__ st0_out,
                                                   const float* __restrict__ st2_in,
                                                   float* __restrict__ st2_out,
                                                   int t0, int CH) {
    int bid = blockIdx.x;            // 0..255
    int b = bid >> 3, w = bid & 7;
    int ocStart = w * 9;
    int nOc = (w == 7) ? 7 : 9;
    int tid = threadIdx.x;
    __shared__ float v0[C1N], i0[C1N], z0[C1N];   // 17.6 KB
    __shared__ float w2s[9 * 750];                // 27 KB
    __shared__ float part[9 * 30 * 9];            // 9.7 KB [ol][ic][pos]
    __shared__ float red[81];                     // [ol][pos]
    for (int e = tid; e < nOc * 750; e += 320) w2s[e] = w2[ocStart * 750 + e];
    float v2 = 0.f, i2 = 0.f;
    if (t0 == 0) {
        for (int e = tid; e < C1N; e += 320) { v0[e] = 0.f; i0[e] = 0.f; }
    } else {
        const float* s0 = st0_in + (size_t)b * 2 * C1N;
        for (int e = tid; e < C1N; e += 320) { v0[e] = s0[e]; i0[e] = s0[C1N + e]; }
        if (tid < nOc) {
            v2 = st2_in[b * ZSEQN + ocStart + tid];
            i2 = st2_in[BATCH * ZSEQN + b * ZSEQN + ocStart + tid];
        }
    }
    float bias2 = (tid < nOc) ? b2[ocStart + tid] : 0.f;
    __syncthreads();
    const float* c1b = c1buf + (size_t)b * CH * C1N;
    float* zs = zbuf + (size_t)b * TSTEPS * ZSEQN;
    int nConv = nOc * 30;
    for (int tc = 0; tc < CH; ++tc) {
        const float* c1t = c1b + (size_t)tc * C1N;
        for (int e = tid; e < C1N; e += 320) {
            float v = v0[e], i = i0[e];
            float vd = v + 0.1f * (i - v);
            float id = i - 0.2f * i;
            bool sp = (vd > 1.0f);
            v0[e] = sp ? 0.f : vd;
            i0[e] = id + c1t[e];
            z0[e] = sp ? 1.f : 0.f;
        }
        __syncthreads();                     // z0 ready
        if (tid < nConv) {
            int ol = tid / 30, ic = tid - ol * 30;
            float zw[49];
            #pragma unroll
            for (int j = 0; j < 49; ++j) zw[j] = z0[ic * 49 + j];
            float a[9];
            #pragma unroll
            for (int p = 0; p < 9; ++p) a[p] = 0.f;
            const float* wb = &w2s[ol * 750 + ic * 25];
            #pragma unroll
            for (int ky = 0; ky < 5; ++ky)
                #pragma unroll
                for (int kx = 0; kx < 5; ++kx) {
                    float wv = wb[ky * 5 + kx];
                    #pragma unroll
                    for (int cy = 0; cy < 3; ++cy)
                        #pragma unroll
                        for (int cx = 0; cx < 3; ++cx)
                            a[cy * 3 + cx] = fmaf(zw[(cy + ky) * 7 + cx + kx], wv, a[cy * 3 + cx]);
                }
            #pragma unroll
            for (int p = 0; p < 9; ++p) part[tid * 9 + p] = a[p];
        }
        __syncthreads();                     // part ready
        if (tid < nOc * 9) {
            int ol = tid / 9, pos = tid - ol * 9;
            float s = 0.f;
            for (int ic = 0; ic < 30; ++ic) s += part[(ol * 30 + ic) * 9 + pos];
            red[tid] = s;
        }
        __syncthreads();                     // red ready
        if (tid < nOc) {
            float m = -1e30f;
            #pragma unroll
            for (int p = 0; p < 9; ++p) m = fmaxf(m, red[tid * 9 + p]);
            float inp = m + bias2;
            float vd = v2 + 0.1f * (i2 - v2);
            float id = i2 - 0.2f * i2;
            bool sp = (vd > 1.0f);
            v2 = sp ? 0.f : vd;
            i2 = id + inp;
            zs[(size_t)(t0 + tc) * ZSEQN + ocStart + tid] = sp ? 1.f : 0.f;
        }
        __syncthreads();
    }
    // persist chunk state (parity buffer -> no read/write race across WGs)
    if (w == 0) {
        float* s0 = st0_out + (size_t)b * 2 * C1N;
        for (int e = tid; e < C1N; e += 320) { s0[e] = v0[e]; s0[C1N + e] = i0[e]; }
    }
    if (tid < nOc) {
        st2_out[b * ZSEQN + ocStart + tid] = v2;
        st2_out[BATCH * ZSEQN + b * ZSEQN + ocStart + tid] = i2;
    }
}

// -------------------------------------------------------------------- K3 ---
__device__ inline float accum_rows(const float* __restrict__ catT,
                                   const unsigned short* list,
                                   int A, int start, int step, int N, int o) {
    float c0 = 0.f, c1 = 0.f, c2 = 0.f, c3 = 0.f;
    int a = start;
    for (; a + 3 * step < A; a += 4 * step) {
        c0 += catT[(size_t)list[a] * N + o];
        c1 += catT[(size_t)list[a + step] * N + o];
        c2 += catT[(size_t)list[a + 2 * step] * N + o];
        c3 += catT[(size_t)list[a + 3 * step] * N + o];
    }
    for (; a < A; a += step) c0 += catT[(size_t)list[a] * N + o];
    return (c0 + c1) + (c2 + c3);
}

// Recurrent chains. 64 WGs: role 0 = l1 (N=512,R=4), role 1 = cl (N=1024,R=10).
// Role segregated by bid%8 so each XCD's L2 tends to hold one weight matrix.
__global__ __launch_bounds__(1024) void rec_chain(const float* __restrict__ fc_out_w,
                                                  const float* __restrict__ cl_fc_w,
                                                  const float* __restrict__ zbuf,
                                                  const float* __restrict__ w1t,
                                                  const float* __restrict__ w2t,
                                                  float* __restrict__ out) {
    int bid = blockIdx.x;
    int r8 = bid & 7, q = bid >> 3;
    int role = (r8 >= 4) ? 1 : 0;
    int b = q * 4 + (r8 & 3);
    int N = role ? HID2 : HID1;
    int K = role ? K2CAT : K1CAT;
    int R = role ? 10 : 4;
    const float* catT = role ? w2t : w1t;
    const float* fcw = role ? cl_fc_w : fc_out_w;
    int tid = threadIdx.x;
    int lane = tid & 63, wid = tid >> 6;     // 16 waves
    __shared__ float z1[HID2];
    __shared__ unsigned short list[K2CAT];
    __shared__ float fcwl[10 * HID2];        // 40 KB
    __shared__ float wpart[10 * 16];
    __shared__ int wcnt[16];
    __shared__ float combuf[HID1];
    __shared__ float mvals[10];
    for (int e = tid; e < R * N; e += 1024) fcwl[e] = fcw[e];
    if (tid < N) z1[tid] = 0.f;
    float v = 0.f, iacc = 0.f;               // lif_rec state for o = tid < N
    float vli = 0.f, ili = 0.f, rmax = -1e30f;  // LI state for tid < R
    const float* zsb = zbuf + (size_t)b * TSTEPS * ZSEQN;
    __syncthreads();
    for (int t = 0; t < TSTEPS; ++t) {
        // ---- build active-index list (ballot compaction) ----
        int A = 0;
        for (int base = 0; base < K; base += 1024) {
            int j = base + tid;
            bool pred = false;
            if (j < K) {
                float val = (j < 70) ? zsb[(size_t)t * ZSEQN + j] : z1[j - 70];
                pred = (val != 0.f);
            }
            unsigned long long mask = __ballot(pred);
            int lanep = __popcll(mask & ((1ull << lane) - 1ull));
            if (lane == 0) wcnt[wid] = __popcll(mask);
            __syncthreads();
            int woff = A, tot = 0;
            for (int ww = 0; ww < 16; ++ww) {
                int c = wcnt[ww];
                if (ww < wid) woff += c;
                tot += c;
            }
            if (pred) list[woff + lanep] = (unsigned short)j;
            A += tot;
            __syncthreads();
        }
        // ---- gather-accumulate active weight rows ----
        float cur = 0.f;
        if (role == 0) {
            int o = tid & 511, half = tid >> 9;
            float c = accum_rows(catT, list, A, half, 2, HID1, o);
            if (half) combuf[o] = c; else cur = c;
        } else {
            cur = accum_rows(catT, list, A, 0, 1, HID2, tid);
        }
        __syncthreads();
        if (role == 0 && tid < HID1) cur += combuf[tid];
        // ---- lif_rec update ----
        float znew = 0.f;
        if (tid < N) {
            float vd = v + 0.1f * (iacc - v);
            float id = iacc - 0.2f * iacc;
            bool sp = (vd > 0.4f);
            znew = sp ? 1.f : 0.f;
            v = sp ? 0.f : vd;
            iacc = id + cur;
            z1[tid] = znew;
        }
        // ---- fc readout: per-wave shuffle reduce, then cross-wave sum ----
        for (int k = 0; k < R; ++k) {
            float c = (tid < N && znew != 0.f) ? fcwl[k * N + tid] : 0.f;
            #pragma unroll
            for (int off = 32; off > 0; off >>= 1) c += __shfl_xor(c, off);
            if (lane == 0) wpart[k * 16 + wid] = c;
        }
        __syncthreads();                     // wpart + z1 ready
        if (tid < R) {
            float inp = 0.f;
            #pragma unroll
            for (int ww = 0; ww < 16; ++ww) inp += wpart[tid * 16 + ww];
            float vn = vli + 0.1f * (ili - vli);
            ili = ili - 0.2f * ili + inp;
            vli = vn;
            rmax = fmaxf(rmax, vn);
        }
        // no end barrier needed: next step's first barrier orders everything
    }
    if (role == 1 && tid < 10) mvals[tid] = rmax;
    __syncthreads();
    if (role == 0) {
        if (tid < 4) out[b * 4 + tid] = rmax;
    } else if (tid < 10) {
        float M = -1e30f;
        #pragma unroll
        for (int k = 0; k < 10; ++k) M = fmaxf(M, mvals[k]);
        float s = 0.f;
        #pragma unroll
        for (int k = 0; k < 10; ++k) s += expf(mvals[k] - M);
        out[BATCH * 4 + b * 10 + tid] = mvals[tid] - M - logf(s);
    }
}

// ---------------------------------------------------------------------------
extern "C" void kernel_launch(void* const* d_in, const int* in_sizes, int n_in,
                              void* d_out, int out_size, void* d_ws, size_t ws_size,
                              hipStream_t stream) {
    const float* x        = (const float*)d_in[0];
    const float* w1       = (const float*)d_in[1];
    const float* b1       = (const float*)d_in[2];
    const float* w2       = (const float*)d_in[3];
    const float* b2       = (const float*)d_in[4];
    const float* l1_in_w  = (const float*)d_in[5];
    const float* l1_rec_w = (const float*)d_in[6];
    const float* fc_out_w = (const float*)d_in[7];
    const float* cl_in_w  = (const float*)d_in[8];
    const float* cl_rec_w = (const float*)d_in[9];
    const float* cl_fc_w  = (const float*)d_in[10];
    float* out = (float*)d_out;
    float* ws  = (float*)d_ws;

    // ---- ws layout (floats), chosen to fit ws_size ----
    size_t base = (size_t)N_Z + N_W1T + N_W2T + 2 * (N_ST0 + N_ST2); // 1,951,360
    size_t avail = ws_size / 4;
    static const int divs[] = {150, 75, 50, 30, 25, 15, 10, 6, 5, 3, 2, 1};
    int CH = 1;
    for (int i = 0; i < 12; ++i) {
        size_t need = base + (size_t)BATCH * divs[i] * C1N;
        if (need <= avail) { CH = divs[i]; break; }
    }
    float* zbuf = ws;                       // N_Z
    float* w1t  = zbuf + N_Z;               // N_W1T
    float* w2t  = w1t + N_W1T;              // N_W2T
    float* st0a = w2t + N_W2T;              // N_ST0
    float* st0b = st0a + N_ST0;             // N_ST0
    float* st2a = st0b + N_ST0;             // N_ST2
    float* st2b = st2a + N_ST2;             // N_ST2
    float* c1buf = st2b + N_ST2;            // BATCH*CH*C1N

    prep_weights<<<dim3(512), dim3(256), 0, stream>>>(l1_in_w, l1_rec_w,
                                                      cl_in_w, cl_rec_w, w1t, w2t);
    int nChunks = TSTEPS / CH;
    for (int c = 0; c < nChunks; ++c) {
        int t0 = c * CH;
        int par = c & 1;
        const float* s0i = par ? st0b : st0a;
        float*       s0o = par ? st0a : st0b;
        const float* s2i = par ? st2b : st2a;
        float*       s2o = par ? st2a : st2b;
        conv1_pool<<<dim3(BATCH * CH), dim3(640), 0, stream>>>(x, w1, b1, c1buf, t0, CH);
        conv2_chain<<<dim3(256), dim3(320), 0, stream>>>(w2, b2, c1buf, zbuf,
                                                         s0i, s0o, s2i, s2o, t0, CH);
    }
    rec_chain<<<dim3(64), dim3(1024), 0, stream>>>(fc_out_w, cl_fc_w, zbuf, w1t, w2t, out);
}

// Round 3
// 1820.838 us; speedup vs baseline: 1.1535x; 1.1535x over previous
//
#include <hip/hip_runtime.h>
#include <math.h>

// ---------------------------------------------------------------------------
// SNN forward:  conv1+pool (parallel, chunked over T) ->
//               [lif0 -> conv2+pool -> lif2] (seq t, chunked, state in ws) ->
//               -> lif_rec(l1)+LI readout, lif_rec(cl)+LI readout (seq t)
// Round-3: rec_chain rewritten for latency: float4 gathers with A-split
// thread mapping, single-ballot bitmask compaction (rows reordered [rec|conv]
// in the transposed weights), 3 barriers/step, conv-z prefetch.
// ---------------------------------------------------------------------------

#define BATCH 32
#define TSTEPS 150
#define C1N 1470            // 30*7*7 (trimmed: pooled conv2 only needs 7x7)
#define ZSEQN 70
#define HID1 512
#define HID2 1024
#define K1CAT 582           // 512 + 70   (rows: [rec | conv])
#define K2CAT 1094          // 1024 + 70

#define N_Z    (BATCH*TSTEPS*ZSEQN)   // 336,000
#define N_W1T  (K1CAT*HID1)           // 297,984
#define N_W2T  (K2CAT*HID2)           // 1,120,256
#define N_ST0  (BATCH*2*C1N)          // 94,080
#define N_ST2  (BATCH*2*ZSEQN)        // 4,480

// -------------------------------------------------------------------- K0 ---
// Transposed concat weights, rows ordered [rec (N) | conv-in (70)].
__global__ void prep_weights(const float* __restrict__ l1_in_w,
                             const float* __restrict__ l1_rec_w,
                             const float* __restrict__ cl_in_w,
                             const float* __restrict__ cl_rec_w,
                             float* __restrict__ w1t,
                             float* __restrict__ w2t) {
    int idx = blockIdx.x * blockDim.x + threadIdx.x;
    int stride = gridDim.x * blockDim.x;
    for (int e = idx; e < N_W1T; e += stride) {
        int j = e / HID1, o = e - j * HID1;
        w1t[e] = (j < HID1) ? l1_rec_w[o * HID1 + j] : l1_in_w[o * 70 + (j - HID1)];
    }
    for (int e = idx; e < N_W2T; e += stride) {
        int j = e / HID2, o = e - j * HID2;
        w2t[e] = (j < HID2) ? cl_rec_w[o * HID2 + j] : cl_in_w[o * 70 + (j - HID2)];
    }
}

// -------------------------------------------------------------------- K1 ---
__global__ __launch_bounds__(640) void conv1_pool(const float* __restrict__ x,
                                                  const float* __restrict__ w1,
                                                  const float* __restrict__ b1,
                                                  float* __restrict__ c1buf,
                                                  int t0, int CH) {
    __shared__ float img[2 * 34 * 34];      // 9.25 KB
    __shared__ float w1s[30 * 2 * 49];      // 11.76 KB
    __shared__ float crow[630 * 21];        // 52.9 KB   [oc*21+cy][cx]
    int bid = blockIdx.x;
    int b = bid / CH, tc = bid - b * CH;
    int t = t0 + tc;
    int tid = threadIdx.x;
    const float* xin = x + (size_t)(b * TSTEPS + t) * 2312;
    for (int e = tid; e < 2312; e += 640) img[e] = xin[e];
    for (int e = tid; e < 2940; e += 640) w1s[e] = w1[e];
    __syncthreads();
    if (tid < 630) {
        int oc = tid / 21, cy = tid - oc * 21;
        float acc[21];
        #pragma unroll
        for (int j = 0; j < 21; ++j) acc[j] = 0.f;
        #pragma unroll
        for (int ic = 0; ic < 2; ++ic) {
            const float* irow0 = &img[ic * 1156];
            const float* wrow = &w1s[(oc * 2 + ic) * 49];
            #pragma unroll
            for (int ky = 0; ky < 7; ++ky) {
                const float* ir = &irow0[(cy + ky) * 34];
                float r[27];
                #pragma unroll
                for (int j = 0; j < 27; ++j) r[j] = ir[j];
                #pragma unroll
                for (int kx = 0; kx < 7; ++kx) {
                    float w = wrow[ky * 7 + kx];
                    #pragma unroll
                    for (int cx = 0; cx < 21; ++cx)
                        acc[cx] = fmaf(r[cx + kx], w, acc[cx]);
                }
            }
        }
        #pragma unroll
        for (int cx = 0; cx < 21; ++cx) crow[tid * 21 + cx] = acc[cx];
    }
    __syncthreads();
    float* c1 = c1buf + (size_t)bid * C1N;
    for (int p = tid; p < C1N; p += 640) {
        int oc = p / 49; int r = p - oc * 49; int py = r / 7, px = r - py * 7;
        float m = -1e30f;
        #pragma unroll
        for (int dy = 0; dy < 3; ++dy) {
            int rowid = oc * 21 + 3 * py + dy;
            #pragma unroll
            for (int dx = 0; dx < 3; ++dx)
                m = fmaxf(m, crow[rowid * 21 + 3 * px + dx]);
        }
        c1[p] = m + b1[oc];
    }
}

// -------------------------------------------------------------------- K2 ---
__global__ __launch_bounds__(320) void conv2_chain(const float* __restrict__ w2,
                                                   const float* __restrict__ b2,
                                                   const float* __restrict__ c1buf,
                                                   float* __restrict__ zbuf,
                                                   const float* __restrict__ st0_in,
                                                   float* __restrict__ st0_out,
                                                   const float* __restrict__ st2_in,
                                                   float* __restrict__ st2_out,
                                                   int t0, int CH) {
    int bid = blockIdx.x;            // 0..255
    int b = bid >> 3, w = bid & 7;
    int ocStart = w * 9;
    int nOc = (w == 7) ? 7 : 9;
    int tid = threadIdx.x;
    __shared__ float v0[C1N], i0[C1N], z0[C1N];   // 17.6 KB
    __shared__ float w2s[9 * 750];                // 27 KB
    __shared__ float part[9 * 30 * 9];            // 9.7 KB [ol][ic][pos]
    __shared__ float red[81];                     // [ol][pos]
    for (int e = tid; e < nOc * 750; e += 320) w2s[e] = w2[ocStart * 750 + e];
    float v2 = 0.f, i2 = 0.f;
    if (t0 == 0) {
        for (int e = tid; e < C1N; e += 320) { v0[e] = 0.f; i0[e] = 0.f; }
    } else {
        const float* s0 = st0_in + (size_t)b * 2 * C1N;
        for (int e = tid; e < C1N; e += 320) { v0[e] = s0[e]; i0[e] = s0[C1N + e]; }
        if (tid < nOc) {
            v2 = st2_in[b * ZSEQN + ocStart + tid];
            i2 = st2_in[BATCH * ZSEQN + b * ZSEQN + ocStart + tid];
        }
    }
    float bias2 = (tid < nOc) ? b2[ocStart + tid] : 0.f;
    __syncthreads();
    const float* c1b = c1buf + (size_t)b * CH * C1N;
    float* zs = zbuf + (size_t)b * TSTEPS * ZSEQN;
    int nConv = nOc * 30;
    for (int tc = 0; tc < CH; ++tc) {
        const float* c1t = c1b + (size_t)tc * C1N;
        for (int e = tid; e < C1N; e += 320) {
            float v = v0[e], i = i0[e];
            float vd = v + 0.1f * (i - v);
            float id = i - 0.2f * i;
            bool sp = (vd > 1.0f);
            v0[e] = sp ? 0.f : vd;
            i0[e] = id + c1t[e];
            z0[e] = sp ? 1.f : 0.f;
        }
        __syncthreads();
        if (tid < nConv) {
            int ol = tid / 30, ic = tid - ol * 30;
            float zw[49];
            #pragma unroll
            for (int j = 0; j < 49; ++j) zw[j] = z0[ic * 49 + j];
            float a[9];
            #pragma unroll
            for (int p = 0; p < 9; ++p) a[p] = 0.f;
            const float* wb = &w2s[ol * 750 + ic * 25];
            #pragma unroll
            for (int ky = 0; ky < 5; ++ky)
                #pragma unroll
                for (int kx = 0; kx < 5; ++kx) {
                    float wv = wb[ky * 5 + kx];
                    #pragma unroll
                    for (int cy = 0; cy < 3; ++cy)
                        #pragma unroll
                        for (int cx = 0; cx < 3; ++cx)
                            a[cy * 3 + cx] = fmaf(zw[(cy + ky) * 7 + cx + kx], wv, a[cy * 3 + cx]);
                }
            #pragma unroll
            for (int p = 0; p < 9; ++p) part[tid * 9 + p] = a[p];
        }
        __syncthreads();
        if (tid < nOc * 9) {
            int ol = tid / 9, pos = tid - ol * 9;
            float s = 0.f;
            for (int ic = 0; ic < 30; ++ic) s += part[(ol * 30 + ic) * 9 + pos];
            red[tid] = s;
        }
        __syncthreads();
        if (tid < nOc) {
            float m = -1e30f;
            #pragma unroll
            for (int p = 0; p < 9; ++p) m = fmaxf(m, red[tid * 9 + p]);
            float inp = m + bias2;
            float vd = v2 + 0.1f * (i2 - v2);
            float id = i2 - 0.2f * i2;
            bool sp = (vd > 1.0f);
            v2 = sp ? 0.f : vd;
            i2 = id + inp;
            zs[(size_t)(t0 + tc) * ZSEQN + ocStart + tid] = sp ? 1.f : 0.f;
        }
        __syncthreads();
    }
    if (w == 0) {
        float* s0 = st0_out + (size_t)b * 2 * C1N;
        for (int e = tid; e < C1N; e += 320) { s0[e] = v0[e]; s0[C1N + e] = i0[e]; }
    }
    if (tid < nOc) {
        st2_out[b * ZSEQN + ocStart + tid] = v2;
        st2_out[BATCH * ZSEQN + b * ZSEQN + ocStart + tid] = i2;
    }
}

// -------------------------------------------------------------------- K3 ---
__device__ __forceinline__ float4 f4add(float4 a, const float4 b) {
    a.x += b.x; a.y += b.y; a.z += b.z; a.w += b.w; return a;
}

// One WG per chain. Thread layout for gather: aid = t/OQ (A-slice),
// qid = t%OQ (output quad, float4). State layout: thread t owns output o=t.
// Active list built from a z-bitmask (one ballot/wave), rows [rec|conv].
template <int ROLE>
__device__ __forceinline__ float rec_body(int b,
                                          const float* __restrict__ fcw,
                                          const float* __restrict__ zbuf,
                                          const float* __restrict__ catT,
                                          float* __restrict__ fcwl,
                                          float* __restrict__ part,
                                          unsigned short* __restrict__ list,
                                          unsigned long long* __restrict__ maskw,
                                          float* __restrict__ wpart) {
    constexpr int N   = ROLE ? HID2 : HID1;
    constexpr int K   = ROLE ? K2CAT : K1CAT;
    constexpr int R   = ROLE ? 10 : 4;
    constexpr int S   = ROLE ? 4 : 8;      // A-split factor
    constexpr int OQ  = 1024 / S;          // output quads (OQ*4 == N)
    constexpr int NW  = N / 64;            // rec bitmask words
    constexpr int WC  = NW + 2;            // + 2 conv words
    constexpr int PLS = N + 8;             // part plane stride
    constexpr int N4  = N / 4;

    const int t = threadIdx.x;
    const int lane = t & 63, wv = t >> 6;
    const int aid = t / OQ, qid = t - aid * OQ;

    for (int e = t; e < R * N; e += 1024) fcwl[e] = fcw[e];

    float v = 0.f, iacc = 0.f, znew = 0.f;
    float vli = 0.f, ili = 0.f, rmax = -1e30f;
    const float* zsb = zbuf + (size_t)b * TSTEPS * ZSEQN;
    const float4* __restrict__ catT4 = (const float4*)catT;

    // ---- list for t=0: rec spikes all zero, conv from zbuf[0] ----
    float zc0 = (t < 70) ? zsb[t] : 0.f;
    if (lane == 0 && wv < NW) maskw[wv] = 0ull;
    unsigned long long mc0 = __ballot(t < 70 && zc0 != 0.f);
    if (lane == 0 && wv < 2) maskw[NW + wv] = mc0;
    __syncthreads();
    int A = 0;
    for (int j = t; j < K; j += 1024) {
        int w = j >> 6;
        unsigned long long m = maskw[w];
        if ((m >> (j & 63)) & 1ull) {
            int pos = __popcll(m & ((1ull << (j & 63)) - 1ull));
            for (int u = 0; u < w; ++u) pos += __popcll(maskw[u]);
            list[pos] = (unsigned short)j;
        }
    }
    #pragma unroll
    for (int u = 0; u < WC; ++u) A += __popcll(maskw[u]);
    __syncthreads();

    for (int tt = 0; tt < TSTEPS; ++tt) {
        // prefetch next step's conv spikes (hidden under the gather)
        float znext = (t < 70 && tt + 1 < TSTEPS) ? zsb[(size_t)(tt + 1) * ZSEQN + t] : 0.f;
        // ---- gather active weight rows (float4, S-strided, ILP4) ----
        float4 s0 = {0.f, 0.f, 0.f, 0.f}, s1 = s0, s2 = s0, s3 = s0;
        int idx = aid;
        for (; idx + 3 * S < A; idx += 4 * S) {
            int r0 = list[idx], r1 = list[idx + S];
            int r2 = list[idx + 2 * S], r3 = list[idx + 3 * S];
            s0 = f4add(s0, catT4[r0 * N4 + qid]);
            s1 = f4add(s1, catT4[r1 * N4 + qid]);
            s2 = f4add(s2, catT4[r2 * N4 + qid]);
            s3 = f4add(s3, catT4[r3 * N4 + qid]);
        }
        for (; idx < A; idx += S) s0 = f4add(s0, catT4[list[idx] * N4 + qid]);
        s0 = f4add(f4add(s0, s1), f4add(s2, s3));
        *(float4*)(part + aid * PLS + 4 * qid) = s0;
        __syncthreads();                                  // B1: part ready
        // ---- state update (thread t owns output o=t) ----
        if (t < N) {
            float cur = 0.f;
            #pragma unroll
            for (int a = 0; a < S; ++a) cur += part[a * PLS + t];
            float vd = v + 0.1f * (iacc - v);
            float id = iacc - 0.2f * iacc;
            bool sp = (vd > 0.4f);
            znew = sp ? 1.f : 0.f;
            v = sp ? 0.f : vd;
            iacc = id + cur;
        }
        // ---- ballots for NEXT step's list ----
        unsigned long long mz = __ballot(znew != 0.f);
        if (lane == 0 && wv < NW) maskw[wv] = mz;
        unsigned long long mc = __ballot(t < 70 && znext != 0.f);
        if (lane == 0 && wv < 2) maskw[NW + wv] = mc;
        // ---- fc partials: per-wave shuffle reduce ----
        #pragma unroll
        for (int k = 0; k < R; ++k) {
            float c = (znew != 0.f) ? fcwl[k * N + t] : 0.f;
            #pragma unroll
            for (int off = 32; off > 0; off >>= 1) c += __shfl_xor(c, off);
            if (lane == 0) wpart[k * 16 + wv] = c;
        }
        __syncthreads();                                  // B2: wpart+maskw
        if (t < R) {
            float inp = 0.f;
            #pragma unroll
            for (int w2 = 0; w2 < 16; ++w2) inp += wpart[t * 16 + w2];
            float vn = vli + 0.1f * (ili - vli);
            ili = ili - 0.2f * ili + inp;
            vli = vn;
            rmax = fmaxf(rmax, vn);
        }
        // ---- build next list (overlaps the LI update) ----
        A = 0;
        for (int j = t; j < K; j += 1024) {
            int w = j >> 6;
            unsigned long long m = maskw[w];
            if ((m >> (j & 63)) & 1ull) {
                int pos = __popcll(m & ((1ull << (j & 63)) - 1ull));
                for (int u = 0; u < w; ++u) pos += __popcll(maskw[u]);
                list[pos] = (unsigned short)j;
            }
        }
        #pragma unroll
        for (int u = 0; u < WC; ++u) A += __popcll(maskw[u]);
        __syncthreads();                                  // B3: list ready
    }
    return rmax;
}

__global__ __launch_bounds__(1024) void rec_chain(const float* __restrict__ fc_out_w,
                                                  const float* __restrict__ cl_fc_w,
                                                  const float* __restrict__ zbuf,
                                                  const float* __restrict__ w1t,
                                                  const float* __restrict__ w2t,
                                                  float* __restrict__ out) {
    __shared__ float fcwl[10 * HID2];          // 40 KB
    __shared__ float part[4160];               // 16.25 KB (max of roles)
    __shared__ unsigned short list[K2CAT];
    __shared__ unsigned long long maskw[18];
    __shared__ float wpart[10 * 16];
    __shared__ float mvals[10];

    int bid = blockIdx.x;
    int r8 = bid & 7, q8 = bid >> 3;
    int role = (r8 >= 4) ? 1 : 0;
    int b = q8 * 4 + (r8 & 3);
    int t = threadIdx.x;

    float rmax;
    if (role) {
        rmax = rec_body<1>(b, cl_fc_w, zbuf, w2t, fcwl, part, list, maskw, wpart);
        if (t < 10) mvals[t] = rmax;
        __syncthreads();
        if (t < 10) {
            float M = -1e30f;
            #pragma unroll
            for (int k = 0; k < 10; ++k) M = fmaxf(M, mvals[k]);
            float s = 0.f;
            #pragma unroll
            for (int k = 0; k < 10; ++k) s += expf(mvals[k] - M);
            out[BATCH * 4 + b * 10 + t] = mvals[t] - M - logf(s);
        }
    } else {
        rmax = rec_body<0>(b, fc_out_w, zbuf, w1t, fcwl, part, list, maskw, wpart);
        if (t < 4) out[b * 4 + t] = rmax;
    }
}

// ---------------------------------------------------------------------------
extern "C" void kernel_launch(void* const* d_in, const int* in_sizes, int n_in,
                              void* d_out, int out_size, void* d_ws, size_t ws_size,
                              hipStream_t stream) {
    const float* x        = (const float*)d_in[0];
    const float* w1       = (const float*)d_in[1];
    const float* b1       = (const float*)d_in[2];
    const float* w2       = (const float*)d_in[3];
    const float* b2       = (const float*)d_in[4];
    const float* l1_in_w  = (const float*)d_in[5];
    const float* l1_rec_w = (const float*)d_in[6];
    const float* fc_out_w = (const float*)d_in[7];
    const float* cl_in_w  = (const float*)d_in[8];
    const float* cl_rec_w = (const float*)d_in[9];
    const float* cl_fc_w  = (const float*)d_in[10];
    float* out = (float*)d_out;
    float* ws  = (float*)d_ws;

    size_t base = (size_t)N_Z + N_W1T + N_W2T + 2 * (N_ST0 + N_ST2);
    size_t avail = ws_size / 4;
    static const int divs[] = {150, 75, 50, 30, 25, 15, 10, 6, 5, 3, 2, 1};
    int CH = 1;
    for (int i = 0; i < 12; ++i) {
        size_t need = base + (size_t)BATCH * divs[i] * C1N;
        if (need <= avail) { CH = divs[i]; break; }
    }
    float* zbuf = ws;
    float* w1t  = zbuf + N_Z;
    float* w2t  = w1t + N_W1T;
    float* st0a = w2t + N_W2T;
    float* st0b = st0a + N_ST0;
    float* st2a = st0b + N_ST0;
    float* st2b = st2a + N_ST2;
    float* c1buf = st2b + N_ST2;

    prep_weights<<<dim3(512), dim3(256), 0, stream>>>(l1_in_w, l1_rec_w,
                                                      cl_in_w, cl_rec_w, w1t, w2t);
    int nChunks = TSTEPS / CH;
    for (int c = 0; c < nChunks; ++c) {
        int t0 = c * CH;
        int par = c & 1;
        const float* s0i = par ? st0b : st0a;
        float*       s0o = par ? st0a : st0b;
        const float* s2i = par ? st2b : st2a;
        float*       s2o = par ? st2a : st2b;
        conv1_pool<<<dim3(BATCH * CH), dim3(640), 0, stream>>>(x, w1, b1, c1buf, t0, CH);
        conv2_chain<<<dim3(256), dim3(320), 0, stream>>>(w2, b2, c1buf, zbuf,
                                                         s0i, s0o, s2i, s2o, t0, CH);
    }
    rec_chain<<<dim3(64), dim3(1024), 0, stream>>>(fc_out_w, cl_fc_w, zbuf, w1t, w2t, out);
}

// Round 4
// 1748.759 us; speedup vs baseline: 1.2011x; 1.0412x over previous
//
#include <hip/hip_runtime.h>
#include <math.h>

// ---------------------------------------------------------------------------
// SNN forward. Round-4: rec_chain column-split 6(role1)/2(role0) WGs per
// chain -> 256 WGs (one per CU), per-step exchange of spike bitmasks + fc
// partials via agent-scope atomics (double-buffered slot + arrive counter).
// Weight stripes pinned per-XCD via bid%8 so each stripe is L2-resident.
// Rationale: round-3 showed the 1-WG-per-chain gather is per-CU load-
// throughput-bound (~1.1MB/step at ~64B/cy); fp32 must stay (spike-flip
// criticality), so the only lever is more CUs per chain.
// ---------------------------------------------------------------------------

#define BATCH 32
#define TSTEPS 150
#define C1N 1470            // 30*7*7 (trimmed: pooled conv2 only needs 7x7)
#define ZSEQN 70
#define HID1 512
#define HID2 1024
#define K1CAT 582           // rows: [rec(512) | conv(70)]
#define K2CAT 1094          // rows: [rec(1024) | conv(70)]
#define CS1 6
#define CS0 2
#define EXCH_STRIDE 512     // u32 per chain (counter @0; slots @8+s*128)

#define N_Z    (BATCH*TSTEPS*ZSEQN)   // 336,000
#define N_W1T  (K1CAT*HID1)           // 297,984
#define N_W2T  (K2CAT*HID2)           // 1,120,256
#define N_EXCH (64*EXCH_STRIDE)       // 32,768 (u32, counted as floats)
#define N_ST0  (BATCH*2*C1N)          // 94,080
#define N_ST2  (BATCH*2*ZSEQN)        // 4,480

// -------------------------------------------------------------------- K0 ---
__global__ void prep_weights(const float* __restrict__ l1_in_w,
                             const float* __restrict__ l1_rec_w,
                             const float* __restrict__ cl_in_w,
                             const float* __restrict__ cl_rec_w,
                             float* __restrict__ w1t,
                             float* __restrict__ w2t) {
    int idx = blockIdx.x * blockDim.x + threadIdx.x;
    int stride = gridDim.x * blockDim.x;
    for (int e = idx; e < N_W1T; e += stride) {
        int j = e / HID1, o = e - j * HID1;
        w1t[e] = (j < HID1) ? l1_rec_w[o * HID1 + j] : l1_in_w[o * 70 + (j - HID1)];
    }
    for (int e = idx; e < N_W2T; e += stride) {
        int j = e / HID2, o = e - j * HID2;
        w2t[e] = (j < HID2) ? cl_rec_w[o * HID2 + j] : cl_in_w[o * 70 + (j - HID2)];
    }
}

__global__ void init_exch(unsigned int* __restrict__ exch) {
    int t = threadIdx.x;
    if (t < 64) exch[t * EXCH_STRIDE] = 0u;
}

// -------------------------------------------------------------------- K1 ---
__global__ __launch_bounds__(640) void conv1_pool(const float* __restrict__ x,
                                                  const float* __restrict__ w1,
                                                  const float* __restrict__ b1,
                                                  float* __restrict__ c1buf,
                                                  int t0, int CH) {
    __shared__ float img[2 * 34 * 34];
    __shared__ float w1s[30 * 2 * 49];
    __shared__ float crow[630 * 21];
    int bid = blockIdx.x;
    int b = bid / CH, tc = bid - b * CH;
    int t = t0 + tc;
    int tid = threadIdx.x;
    const float* xin = x + (size_t)(b * TSTEPS + t) * 2312;
    for (int e = tid; e < 2312; e += 640) img[e] = xin[e];
    for (int e = tid; e < 2940; e += 640) w1s[e] = w1[e];
    __syncthreads();
    if (tid < 630) {
        int oc = tid / 21, cy = tid - oc * 21;
        float acc[21];
        #pragma unroll
        for (int j = 0; j < 21; ++j) acc[j] = 0.f;
        #pragma unroll
        for (int ic = 0; ic < 2; ++ic) {
            const float* irow0 = &img[ic * 1156];
            const float* wrow = &w1s[(oc * 2 + ic) * 49];
            #pragma unroll
            for (int ky = 0; ky < 7; ++ky) {
                const float* ir = &irow0[(cy + ky) * 34];
                float r[27];
                #pragma unroll
                for (int j = 0; j < 27; ++j) r[j] = ir[j];
                #pragma unroll
                for (int kx = 0; kx < 7; ++kx) {
                    float w = wrow[ky * 7 + kx];
                    #pragma unroll
                    for (int cx = 0; cx < 21; ++cx)
                        acc[cx] = fmaf(r[cx + kx], w, acc[cx]);
                }
            }
        }
        #pragma unroll
        for (int cx = 0; cx < 21; ++cx) crow[tid * 21 + cx] = acc[cx];
    }
    __syncthreads();
    float* c1 = c1buf + (size_t)bid * C1N;
    for (int p = tid; p < C1N; p += 640) {
        int oc = p / 49; int r = p - oc * 49; int py = r / 7, px = r - py * 7;
        float m = -1e30f;
        #pragma unroll
        for (int dy = 0; dy < 3; ++dy) {
            int rowid = oc * 21 + 3 * py + dy;
            #pragma unroll
            for (int dx = 0; dx < 3; ++dx)
                m = fmaxf(m, crow[rowid * 21 + 3 * px + dx]);
        }
        c1[p] = m + b1[oc];
    }
}

// -------------------------------------------------------------------- K2 ---
__global__ __launch_bounds__(320) void conv2_chain(const float* __restrict__ w2,
                                                   const float* __restrict__ b2,
                                                   const float* __restrict__ c1buf,
                                                   float* __restrict__ zbuf,
                                                   const float* __restrict__ st0_in,
                                                   float* __restrict__ st0_out,
                                                   const float* __restrict__ st2_in,
                                                   float* __restrict__ st2_out,
                                                   int t0, int CH) {
    int bid = blockIdx.x;
    int b = bid >> 3, w = bid & 7;
    int ocStart = w * 9;
    int nOc = (w == 7) ? 7 : 9;
    int tid = threadIdx.x;
    __shared__ float v0[C1N], i0[C1N], z0[C1N];
    __shared__ float w2s[9 * 750];
    __shared__ float part[9 * 30 * 9];
    __shared__ float red[81];
    for (int e = tid; e < nOc * 750; e += 320) w2s[e] = w2[ocStart * 750 + e];
    float v2 = 0.f, i2 = 0.f;
    if (t0 == 0) {
        for (int e = tid; e < C1N; e += 320) { v0[e] = 0.f; i0[e] = 0.f; }
    } else {
        const float* s0 = st0_in + (size_t)b * 2 * C1N;
        for (int e = tid; e < C1N; e += 320) { v0[e] = s0[e]; i0[e] = s0[C1N + e]; }
        if (tid < nOc) {
            v2 = st2_in[b * ZSEQN + ocStart + tid];
            i2 = st2_in[BATCH * ZSEQN + b * ZSEQN + ocStart + tid];
        }
    }
    float bias2 = (tid < nOc) ? b2[ocStart + tid] : 0.f;
    __syncthreads();
    const float* c1b = c1buf + (size_t)b * CH * C1N;
    float* zs = zbuf + (size_t)b * TSTEPS * ZSEQN;
    int nConv = nOc * 30;
    for (int tc = 0; tc < CH; ++tc) {
        const float* c1t = c1b + (size_t)tc * C1N;
        for (int e = tid; e < C1N; e += 320) {
            float v = v0[e], i = i0[e];
            float vd = v + 0.1f * (i - v);
            float id = i - 0.2f * i;
            bool sp = (vd > 1.0f);
            v0[e] = sp ? 0.f : vd;
            i0[e] = id + c1t[e];
            z0[e] = sp ? 1.f : 0.f;
        }
        __syncthreads();
        if (tid < nConv) {
            int ol = tid / 30, ic = tid - ol * 30;
            float zw[49];
            #pragma unroll
            for (int j = 0; j < 49; ++j) zw[j] = z0[ic * 49 + j];
            float a[9];
            #pragma unroll
            for (int p = 0; p < 9; ++p) a[p] = 0.f;
            const float* wb = &w2s[ol * 750 + ic * 25];
            #pragma unroll
            for (int ky = 0; ky < 5; ++ky)
                #pragma unroll
                for (int kx = 0; kx < 5; ++kx) {
                    float wv = wb[ky * 5 + kx];
                    #pragma unroll
                    for (int cy = 0; cy < 3; ++cy)
                        #pragma unroll
                        for (int cx = 0; cx < 3; ++cx)
                            a[cy * 3 + cx] = fmaf(zw[(cy + ky) * 7 + cx + kx], wv, a[cy * 3 + cx]);
                }
            #pragma unroll
            for (int p = 0; p < 9; ++p) part[tid * 9 + p] = a[p];
        }
        __syncthreads();
        if (tid < nOc * 9) {
            int ol = tid / 9, pos = tid - ol * 9;
            float s = 0.f;
            for (int ic = 0; ic < 30; ++ic) s += part[(ol * 30 + ic) * 9 + pos];
            red[tid] = s;
        }
        __syncthreads();
        if (tid < nOc) {
            float m = -1e30f;
            #pragma unroll
            for (int p = 0; p < 9; ++p) m = fmaxf(m, red[tid * 9 + p]);
            float inp = m + bias2;
            float vd = v2 + 0.1f * (i2 - v2);
            float id = i2 - 0.2f * i2;
            bool sp = (vd > 1.0f);
            v2 = sp ? 0.f : vd;
            i2 = id + inp;
            zs[(size_t)(t0 + tc) * ZSEQN + ocStart + tid] = sp ? 1.f : 0.f;
        }
        __syncthreads();
    }
    if (w == 0) {
        float* s0 = st0_out + (size_t)b * 2 * C1N;
        for (int e = tid; e < C1N; e += 320) { s0[e] = v0[e]; s0[C1N + e] = i0[e]; }
    }
    if (tid < nOc) {
        st2_out[b * ZSEQN + ocStart + tid] = v2;
        st2_out[BATCH * ZSEQN + b * ZSEQN + ocStart + tid] = i2;
    }
}

// -------------------------------------------------------------------- K3 ---
__device__ __forceinline__ float4 f4add(float4 a, const float4 b) {
    a.x += b.x; a.y += b.y; a.z += b.z; a.w += b.w; return a;
}
__device__ __forceinline__ void ast(unsigned int* p, unsigned int v) {
    __hip_atomic_store(p, v, __ATOMIC_RELAXED, __HIP_MEMORY_SCOPE_AGENT);
}
__device__ __forceinline__ unsigned int ald(unsigned int* p) {
    return __hip_atomic_load(p, __ATOMIC_RELAXED, __HIP_MEMORY_SCOPE_AGENT);
}

// 256 WGs, 1/CU. bid%8 -> stripe class (heuristic XCD pin): 0..5 role1
// stripes, 6..7 role0 stripes. bid/8 -> chain (batch).
__global__ __launch_bounds__(1024) void rec_chain_mw(const float* __restrict__ fc_out_w,
                                                     const float* __restrict__ cl_fc_w,
                                                     const float* __restrict__ zbuf,
                                                     const float* __restrict__ w1t,
                                                     const float* __restrict__ w2t,
                                                     unsigned int* __restrict__ exch,
                                                     float* __restrict__ out) {
    __shared__ float fcwl[1920];           // R*cols <= 10*192
    __shared__ float part[4224];           // S*(cols+4) max
    __shared__ unsigned short list[K2CAT];
    __shared__ unsigned int maskw[36];
    __shared__ float wpart[160];
    __shared__ float fcbuf[60];
    __shared__ float mvals[10];

    const int bid = blockIdx.x;
    const int xcd = bid & 7, bq = bid >> 3;
    const int role = (xcd < 6) ? 1 : 0;
    const int b = bq;
    const int w = role ? xcd : (xcd - 6);
    const int CS = role ? CS1 : CS0;
    const int N = role ? HID2 : HID1;
    const int K = role ? K2CAT : K1CAT;
    const int R = role ? 10 : 4;
    const int NW32 = N >> 5;
    const int NWT = NW32 + 3;
    const int c0 = role ? ((w < 4) ? 192 * w : 768 + 128 * (w - 4)) : 256 * w;
    const int cols = role ? ((w < 4) ? 192 : 128) : 256;
    const int qcnt = cols >> 2;
    const int S = 1024 / qcnt;             // 21 / 32 / 16
    const int q0 = c0 >> 2;
    const int N4 = N >> 2;
    const int pstr = cols + 4;
    const float4* __restrict__ catT4 = (const float4*)(role ? w2t : w1t);
    const float* fcw = role ? cl_fc_w : fc_out_w;
    unsigned int* ex = exch + (size_t)(role * 32 + b) * EXCH_STRIDE;
    unsigned int* cnt = ex;

    const int t = threadIdx.x;
    const int lane = t & 63, wv = t >> 6;
    const int aid = t / qcnt, qid = t - aid * qcnt;
    const bool gact = (aid < S);

    for (int e = t; e < R * cols; e += 1024)
        fcwl[e] = fcw[(e / cols) * N + c0 + (e % cols)];

    float v = 0.f, iacc = 0.f;
    float vli = 0.f, ili = 0.f, rmax = -1e30f;   // leader threads t<R
    const float* zsb = zbuf + (size_t)b * TSTEPS * ZSEQN;

    // ---- initial list (tt=0): rec bits zero, conv bits from zsb[0] ----
    if (t < NW32) maskw[t] = 0u;
    {
        float zc = (t < 70) ? zsb[t] : 0.f;
        unsigned long long mc = __ballot(t < 70 && zc != 0.f);
        if (lane == 0 && wv < 2) {
            if (wv == 0) { maskw[NW32] = (unsigned)(mc & 0xffffffffull);
                           maskw[NW32 + 1] = (unsigned)(mc >> 32); }
            else         { maskw[NW32 + 2] = (unsigned)(mc & 0x3full); }
        }
    }
    __syncthreads();
    int A = 0;
    for (int u = 0; u < NWT; ++u) A += __popc(maskw[u]);
    for (int jj = t; jj < K; jj += 1024) {
        int wd = jj >> 5;
        unsigned m = maskw[wd];
        if ((m >> (jj & 31)) & 1u) {
            int pos = __popc(m & ((1u << (jj & 31)) - 1u));
            for (int u = 0; u < wd; ++u) pos += __popc(maskw[u]);
            list[pos] = (unsigned short)jj;
        }
    }
    __syncthreads();

    for (int tt = 0; tt < TSTEPS; ++tt) {
        float znext = (t < 70 && tt + 1 < TSTEPS) ? zsb[(size_t)(tt + 1) * ZSEQN + t] : 0.f;
        // ---- stripe gather over active rows ----
        if (gact) {
            float4 s0 = {0.f,0.f,0.f,0.f}, s1 = s0, s2 = s0, s3 = s0;
            int idx = aid;
            for (; idx + 3 * S < A; idx += 4 * S) {
                s0 = f4add(s0, catT4[list[idx] * N4 + q0 + qid]);
                s1 = f4add(s1, catT4[list[idx + S] * N4 + q0 + qid]);
                s2 = f4add(s2, catT4[list[idx + 2 * S] * N4 + q0 + qid]);
                s3 = f4add(s3, catT4[list[idx + 3 * S] * N4 + q0 + qid]);
            }
            for (; idx < A; idx += S) s0 = f4add(s0, catT4[list[idx] * N4 + q0 + qid]);
            s0 = f4add(f4add(s0, s1), f4add(s2, s3));
            *(float4*)(part + aid * pstr + 4 * qid) = s0;
        }
        __syncthreads();                                   // B1: part ready
        float znew = 0.f;
        if (t < cols) {
            float cur = 0.f;
            for (int a = 0; a < S; ++a) cur += part[a * pstr + t];
            float vd = v + 0.1f * (iacc - v);
            float id = iacc - 0.2f * iacc;
            bool sp = (vd > 0.4f);
            znew = sp ? 1.f : 0.f;
            v = sp ? 0.f : vd;
            iacc = id + cur;
        }
        unsigned int* slot = ex + 8 + (tt & 1) * 128;
        unsigned long long mz = __ballot(znew != 0.f);
        if (lane == 0 && (wv << 6) < cols) {
            int wb = (c0 >> 5) + (wv << 1);
            ast(slot + wb, (unsigned)(mz & 0xffffffffull));
            ast(slot + wb + 1, (unsigned)(mz >> 32));
        }
        // ---- fc partials over own cols ----
        for (int k = 0; k < R; ++k) {
            float c = (t < cols && znew != 0.f) ? fcwl[k * cols + t] : 0.f;
            #pragma unroll
            for (int off = 32; off > 0; off >>= 1) c += __shfl_xor(c, off);
            if (lane == 0) wpart[k * 16 + wv] = c;
        }
        __syncthreads();                                   // B2: wpart (+mask stores drained)
        if (t < R) {
            float sum = 0.f;
            #pragma unroll
            for (int u = 0; u < 16; ++u) sum += wpart[t * 16 + u];
            ast(slot + 40 + w * R + t, __float_as_uint(sum));
        }
        __syncthreads();                                   // B3: fcp stores drained
        if (t == 0) {
            atomicAdd(cnt, 1u);
            unsigned target = (unsigned)(CS * (tt + 1));
            while (ald(cnt) < target) __builtin_amdgcn_s_sleep(8);
        }
        __syncthreads();                                   // B4: all arrived
        if (t < NW32) maskw[t] = ald(slot + t);
        {
            unsigned long long mc = __ballot(t < 70 && znext != 0.f);
            if (lane == 0 && wv < 2) {
                if (wv == 0) { maskw[NW32] = (unsigned)(mc & 0xffffffffull);
                               maskw[NW32 + 1] = (unsigned)(mc >> 32); }
                else         { maskw[NW32 + 2] = (unsigned)(mc & 0x3full); }
            }
        }
        if (w == 0 && t < CS * R) fcbuf[t] = __uint_as_float(ald(slot + 40 + t));
        __syncthreads();                                   // B5: maskw + fcbuf
        if (w == 0 && t < R) {
            float inp = 0.f;
            for (int u = 0; u < CS; ++u) inp += fcbuf[u * R + t];
            float vn = vli + 0.1f * (ili - vli);
            ili = ili - 0.2f * ili + inp;
            vli = vn;
            rmax = fmaxf(rmax, vn);
        }
        A = 0;
        for (int u = 0; u < NWT; ++u) A += __popc(maskw[u]);
        for (int jj = t; jj < K; jj += 1024) {
            int wd = jj >> 5;
            unsigned m = maskw[wd];
            if ((m >> (jj & 31)) & 1u) {
                int pos = __popc(m & ((1u << (jj & 31)) - 1u));
                for (int u = 0; u < wd; ++u) pos += __popc(maskw[u]);
                list[pos] = (unsigned short)jj;
            }
        }
        __syncthreads();                                   // B6: list ready
    }

    if (w == 0) {
        if (role == 1) {
            if (t < 10) mvals[t] = rmax;
            __syncthreads();
            if (t < 10) {
                float M = -1e30f;
                #pragma unroll
                for (int k = 0; k < 10; ++k) M = fmaxf(M, mvals[k]);
                float s = 0.f;
                #pragma unroll
                for (int k = 0; k < 10; ++k) s += expf(mvals[k] - M);
                out[BATCH * 4 + b * 10 + t] = mvals[t] - M - logf(s);
            }
        } else {
            if (t < 4) out[b * 4 + t] = rmax;
        }
    }
}

// ---------------------------------------------------------------------------
extern "C" void kernel_launch(void* const* d_in, const int* in_sizes, int n_in,
                              void* d_out, int out_size, void* d_ws, size_t ws_size,
                              hipStream_t stream) {
    const float* x        = (const float*)d_in[0];
    const float* w1       = (const float*)d_in[1];
    const float* b1       = (const float*)d_in[2];
    const float* w2       = (const float*)d_in[3];
    const float* b2       = (const float*)d_in[4];
    const float* l1_in_w  = (const float*)d_in[5];
    const float* l1_rec_w = (const float*)d_in[6];
    const float* fc_out_w = (const float*)d_in[7];
    const float* cl_in_w  = (const float*)d_in[8];
    const float* cl_rec_w = (const float*)d_in[9];
    const float* cl_fc_w  = (const float*)d_in[10];
    float* out = (float*)d_out;
    float* ws  = (float*)d_ws;

    size_t base = (size_t)N_Z + N_W1T + N_W2T + N_EXCH + 2 * (N_ST0 + N_ST2);
    size_t avail = ws_size / 4;
    static const int divs[] = {150, 75, 50, 30, 25, 15, 10, 6, 5, 3, 2, 1};
    int CH = 1;
    for (int i = 0; i < 12; ++i) {
        size_t need = base + (size_t)BATCH * divs[i] * C1N;
        if (need <= avail) { CH = divs[i]; break; }
    }
    float* zbuf = ws;
    float* w1t  = zbuf + N_Z;
    float* w2t  = w1t + N_W1T;
    unsigned int* exch = (unsigned int*)(w2t + N_W2T);
    float* st0a = w2t + N_W2T + N_EXCH;
    float* st0b = st0a + N_ST0;
    float* st2a = st0b + N_ST0;
    float* st2b = st2a + N_ST2;
    float* c1buf = st2b + N_ST2;

    prep_weights<<<dim3(512), dim3(256), 0, stream>>>(l1_in_w, l1_rec_w,
                                                      cl_in_w, cl_rec_w, w1t, w2t);
    init_exch<<<dim3(1), dim3(64), 0, stream>>>(exch);
    int nChunks = TSTEPS / CH;
    for (int c = 0; c < nChunks; ++c) {
        int t0 = c * CH;
        int par = c & 1;
        const float* s0i = par ? st0b : st0a;
        float*       s0o = par ? st0a : st0b;
        const float* s2i = par ? st2b : st2a;
        float*       s2o = par ? st2a : st2b;
        conv1_pool<<<dim3(BATCH * CH), dim3(640), 0, stream>>>(x, w1, b1, c1buf, t0, CH);
        conv2_chain<<<dim3(256), dim3(320), 0, stream>>>(w2, b2, c1buf, zbuf,
                                                         s0i, s0o, s2i, s2o, t0, CH);
    }
    rec_chain_mw<<<dim3(256), dim3(1024), 0, stream>>>(fc_out_w, cl_fc_w, zbuf,
                                                       w1t, w2t, exch, out);
}